// Round 4
// baseline (1869.076 us; speedup 1.0000x reference)
//
#include <hip/hip_runtime.h>
#include <hip/hip_bf16.h>

#define NNODES 100000
#define NEDGES 1600000
#define DF 128
#define NC 40

typedef __bf16 bf16x8 __attribute__((ext_vector_type(8)));
typedef float f32x4 __attribute__((ext_vector_type(4)));

__device__ __forceinline__ unsigned short f2bf(float f) {
    unsigned int u = __builtin_bit_cast(unsigned int, f);
    u = (u + 0x7FFFu + ((u >> 16) & 1u)) >> 16;   // RNE
    return (unsigned short)u;
}
__device__ __forceinline__ float bf2f(unsigned short s) {
    unsigned int u = ((unsigned int)s) << 16;
    return __builtin_bit_cast(float, u);
}

// ---------------- dtype detection.
// flags[0]: edge_index is int64 (odd 32-bit words of first 1024 pairs all 0).
// flags[1]: float tensors are bf16-packed. Test: low-ushort exponent field of
// x's first 4096 words. Packed bf16 N(0,1): exp in [100,140] ~100% of the
// time. fp32 mantissa bits: uniform -> ~16%. Threshold 60%.
__global__ void k_detect(const unsigned int* __restrict__ ei32,
                         const unsigned int* __restrict__ x32,
                         int* __restrict__ flags) {
    __shared__ unsigned int rOr[256];
    __shared__ int rCnt[256];
    unsigned int o = 0; int c = 0;
    for (int i = threadIdx.x; i < 1024; i += 256) o |= ei32[2 * i + 1];
    for (int i = threadIdx.x; i < 4096; i += 256) {
        unsigned int e = (x32[i] >> 7) & 0xFFu;
        c += (e >= 100u && e <= 140u) ? 1 : 0;
    }
    rOr[threadIdx.x] = o; rCnt[threadIdx.x] = c;
    __syncthreads();
    for (int s = 128; s; s >>= 1) {
        if ((int)threadIdx.x < s) {
            rOr[threadIdx.x] |= rOr[threadIdx.x + s];
            rCnt[threadIdx.x] += rCnt[threadIdx.x + s];
        }
        __syncthreads();
    }
    if (threadIdx.x == 0) {
        flags[0] = (rOr[0] == 0u) ? 1 : 0;
        flags[1] = (rCnt[0] > 2457) ? 1 : 0;   // 60% of 4096
    }
}

// ---------------- edge_index -> compact int32
__global__ __launch_bounds__(256) void k_cvt_idx(const void* __restrict__ ei,
                                                 const int* __restrict__ flags,
                                                 int* __restrict__ out, int n) {
    int i = blockIdx.x * 256 + threadIdx.x;
    if (i >= n) return;
    if (flags[0])
        out[i] = (int)((const long long*)ei)[i];
    else
        out[i] = ((const int*)ei)[i];
}

// ---------------- features -> canonical bf16
__global__ __launch_bounds__(256) void k_cvt_feat(const void* __restrict__ src,
                                                  const int* __restrict__ flags,
                                                  unsigned short* __restrict__ dst, int n) {
    int i = blockIdx.x * 256 + threadIdx.x;
    if (i >= n) return;
    dst[i] = flags[1] ? ((const unsigned short*)src)[i]
                      : f2bf(((const float*)src)[i]);
}

// ---------------- bias -> canonical fp32
__global__ void k_cvt_bias(const void* __restrict__ src,
                           const int* __restrict__ flags,
                           float* __restrict__ dst, int n) {
    int i = blockIdx.x * 256 + threadIdx.x;
    if (i >= n) return;
    dst[i] = flags[1] ? bf2f(((const unsigned short*)src)[i])
                      : ((const float*)src)[i];
}

// ---------------- weight transpose -> canonical bf16: dst[n*K+k] = src[k*N+n]
__global__ void k_transpose(const void* __restrict__ src,
                            const int* __restrict__ flags,
                            unsigned short* __restrict__ dst, int K, int N) {
    int idx = blockIdx.x * 256 + threadIdx.x;
    if (idx >= K * N) return;
    int k = idx / N, n = idx - k * N;
    unsigned short v = flags[1] ? ((const unsigned short*)src)[idx]
                                : f2bf(((const float*)src)[idx]);
    dst[n * K + k] = v;
}

// ---------------- scatter-add aggregation: agg[dst] += feat[src] (bf16 -> fp32)
// 128 threads per edge (one per feature). NEDGES*128 = grid*256 exactly.
__global__ __launch_bounds__(256) void k_scatter(const unsigned short* __restrict__ feat,
                                                 const int* __restrict__ src,
                                                 const int* __restrict__ dst,
                                                 float* __restrict__ agg) {
    unsigned int i = blockIdx.x * 256u + threadIdx.x;
    unsigned int e = i >> 7;
    unsigned int c = i & 127u;
    int s = src[e];
    int d = dst[e];
    atomicAdd(&agg[d * DF + c], bf2f(feat[s * DF + c]));
}

// ---------------- prep: out = bf16(bf2f(x) + agg)
__global__ __launch_bounds__(256) void k_prep(const unsigned short* __restrict__ x,
                                              const float* __restrict__ agg,
                                              unsigned short* __restrict__ out, int n4) {
    int i = blockIdx.x * 256 + threadIdx.x;
    if (i >= n4) return;
    ushort4 a = ((const ushort4*)x)[i];
    float4 b = ((const float4*)agg)[i];
    ushort4 r;
    r.x = f2bf(bf2f(a.x) + b.x);
    r.y = f2bf(bf2f(a.y) + b.y);
    r.z = f2bf(bf2f(a.z) + b.z);
    r.w = f2bf(bf2f(a.w) + b.w);
    ((ushort4*)out)[i] = r;
}

// ---------------- MFMA GEMM: C[M x 128] = act(A @ W + bias), bf16 in/out, fp32 acc.
// Verified layouts (m89/m91): A[m=lane&15][k=quad*8+j]; B[k=quad*8+j][n=lane&15];
// D: col=lane&15, row=quad*4+reg.
__global__ __launch_bounds__(256) void k_gemm128(const unsigned short* __restrict__ A,
                                                 const unsigned short* __restrict__ WT,
                                                 const float* __restrict__ bias,
                                                 unsigned short* __restrict__ out,
                                                 int M, int relu) {
    int tid = threadIdx.x;
    int wave = tid >> 6, lane = tid & 63;
    int m = lane & 15, quad = lane >> 4;
    int tile = blockIdx.x * 4 + wave;
    int r0 = tile * 16;
    if (r0 >= M) return;

    const unsigned short* Ab = A + (r0 + m) * DF + quad * 8;
    bf16x8 a[4];
#pragma unroll
    for (int ks = 0; ks < 4; ks++) a[ks] = *(const bf16x8*)(Ab + ks * 32);

    f32x4 acc[8];
#pragma unroll
    for (int nt = 0; nt < 8; nt++) acc[nt] = (f32x4){0.f, 0.f, 0.f, 0.f};

#pragma unroll
    for (int nt = 0; nt < 8; nt++) {
        const unsigned short* Bb = WT + (nt * 16 + m) * DF + quad * 8;
#pragma unroll
        for (int ks = 0; ks < 4; ks++) {
            bf16x8 b = *(const bf16x8*)(Bb + ks * 32);
            acc[nt] = __builtin_amdgcn_mfma_f32_16x16x32_bf16(a[ks], b, acc[nt], 0, 0, 0);
        }
    }

#pragma unroll
    for (int nt = 0; nt < 8; nt++) {
        int col = nt * 16 + m;
        float bv = bias[col];
#pragma unroll
        for (int reg = 0; reg < 4; reg++) {
            int row = r0 + quad * 4 + reg;
            float v = acc[nt][reg] + bv;
            if (relu && v < 0.f) v = 0.f;
            out[row * DF + col] = f2bf(v);
        }
    }
}

// ---------------- fc (128 -> 40) + log_softmax fused. One wave per row.
// Output dtype matches detected dataset dtype (flags[1]).
__global__ __launch_bounds__(256) void k_fc_lsm(const unsigned short* __restrict__ H,
                                                const unsigned short* __restrict__ WfcT,
                                                const float* __restrict__ bfc,
                                                const int* __restrict__ flags,
                                                void* __restrict__ out) {
    int col = threadIdx.x;                       // 0..63
    int row = blockIdx.x * 4 + threadIdx.y;      // 25000 * 4 = 100000 exactly
    bool act = col < NC;
    const unsigned short* h = H + row * DF;
    const unsigned short* w = WfcT + (act ? col : 0) * DF;
    float acc = act ? bfc[col] : 0.f;
#pragma unroll 8
    for (int k = 0; k < DF; k++) acc += bf2f(h[k]) * bf2f(w[k]);

    float v = act ? acc : -1e30f;
#pragma unroll
    for (int off = 32; off; off >>= 1) {
        float o = __shfl_xor(v, off, 64);
        v = v > o ? v : o;
    }
    float mx = v;
    float e = act ? __expf(acc - mx) : 0.f;
#pragma unroll
    for (int off = 32; off; off >>= 1) e += __shfl_xor(e, off, 64);
    if (act) {
        float r = acc - mx - __logf(e);
        if (flags[1])
            ((unsigned short*)out)[row * NC + col] = f2bf(r);
        else
            ((float*)out)[row * NC + col] = r;
    }
}

extern "C" void kernel_launch(void* const* d_in, const int* in_sizes, int n_in,
                              void* d_out, int out_size, void* d_ws, size_t ws_size,
                              hipStream_t stream) {
    const void* x   = d_in[0];
    const void* ei  = d_in[1];
    const void* w1a = d_in[2];
    const void* b1a = d_in[3];
    const void* w1b = d_in[4];
    const void* b1b = d_in[5];
    const void* w2a = d_in[6];
    const void* b2a = d_in[7];
    const void* w2b = d_in[8];
    const void* b2b = d_in[9];
    const void* wfc = d_in[10];
    const void* bfc = d_in[11];

    char* ws = (char*)d_ws;
    size_t off = 0;
    auto alloc = [&](size_t bytes) {
        void* p = ws + off;
        off += (bytes + 255) & ~(size_t)255;
        return p;
    };
    float*          agg  = (float*)alloc((size_t)NNODES * DF * 4);
    unsigned short* xc   = (unsigned short*)alloc((size_t)NNODES * DF * 2);
    unsigned short* h1   = (unsigned short*)alloc((size_t)NNODES * DF * 2);
    unsigned short* Abf  = (unsigned short*)alloc((size_t)NNODES * DF * 2);
    unsigned short* T1   = (unsigned short*)alloc((size_t)NNODES * DF * 2);
    int*            idx  = (int*)alloc((size_t)2 * NEDGES * 4);
    int*            flags= (int*)alloc(256);
    unsigned short* w1aT = (unsigned short*)alloc(128 * 128 * 2);
    unsigned short* w1bT = (unsigned short*)alloc(128 * 128 * 2);
    unsigned short* w2aT = (unsigned short*)alloc(128 * 128 * 2);
    unsigned short* w2bT = (unsigned short*)alloc(128 * 128 * 2);
    unsigned short* wfcT = (unsigned short*)alloc(NC * 128 * 2);
    float*          b1af = (float*)alloc(128 * 4);
    float*          b1bf = (float*)alloc(128 * 4);
    float*          b2af = (float*)alloc(128 * 4);
    float*          b2bf = (float*)alloc(128 * 4);
    float*          bfcf = (float*)alloc(NC * 4);

    // ---- dtype detection + normalization to canonical (bf16 feats, fp32 bias)
    k_detect<<<1, 256, 0, stream>>>((const unsigned int*)ei, (const unsigned int*)x, flags);
    k_cvt_idx<<<(2 * NEDGES + 255) / 256, 256, 0, stream>>>(ei, flags, idx, 2 * NEDGES);
    k_cvt_feat<<<(NNODES * DF + 255) / 256, 256, 0, stream>>>(x, flags, xc, NNODES * DF);
    const int* src = idx;
    const int* dst = idx + NEDGES;

    int wblk = (128 * 128 + 255) / 256;
    k_transpose<<<wblk, 256, 0, stream>>>(w1a, flags, w1aT, 128, 128);
    k_transpose<<<wblk, 256, 0, stream>>>(w1b, flags, w1bT, 128, 128);
    k_transpose<<<wblk, 256, 0, stream>>>(w2a, flags, w2aT, 128, 128);
    k_transpose<<<wblk, 256, 0, stream>>>(w2b, flags, w2bT, 128, 128);
    k_transpose<<<(128 * NC + 255) / 256, 256, 0, stream>>>(wfc, flags, wfcT, 128, NC);
    k_cvt_bias<<<1, 256, 0, stream>>>(b1a, flags, b1af, 128);
    k_cvt_bias<<<1, 256, 0, stream>>>(b1b, flags, b1bf, 128);
    k_cvt_bias<<<1, 256, 0, stream>>>(b2a, flags, b2af, 128);
    k_cvt_bias<<<1, 256, 0, stream>>>(b2b, flags, b2bf, 128);
    k_cvt_bias<<<1, 256, 0, stream>>>(bfc, flags, bfcf, NC);

    const size_t aggBytes = (size_t)NNODES * DF * 4;
    const int scatterGrid = NEDGES / 2;          // NEDGES*128 threads / 256 = 800000
    const int prepGrid = (NNODES * DF / 4 + 255) / 256;
    const int gemmGrid = (NNODES / 16 + 3) / 4;  // 6250 tiles / 4 waves

    // ---- layer 1
    hipMemsetAsync(agg, 0, aggBytes, stream);
    k_scatter<<<scatterGrid, 256, 0, stream>>>(xc, src, dst, agg);
    k_prep<<<prepGrid, 256, 0, stream>>>(xc, agg, Abf, NNODES * DF / 4);
    k_gemm128<<<gemmGrid, 256, 0, stream>>>(Abf, w1aT, b1af, T1, NNODES, 1);
    k_gemm128<<<gemmGrid, 256, 0, stream>>>(T1, w1bT, b1bf, h1, NNODES, 1);

    // ---- layer 2
    hipMemsetAsync(agg, 0, aggBytes, stream);
    k_scatter<<<scatterGrid, 256, 0, stream>>>(h1, src, dst, agg);
    k_prep<<<prepGrid, 256, 0, stream>>>(h1, agg, Abf, NNODES * DF / 4);
    k_gemm128<<<gemmGrid, 256, 0, stream>>>(Abf, w2aT, b2af, T1, NNODES, 1);
    k_gemm128<<<gemmGrid, 256, 0, stream>>>(T1, w2bT, b2bf, Abf, NNODES, 1);  // H2

    // ---- fc + log_softmax (output dtype per flags[1])
    k_fc_lsm<<<NNODES / 4, dim3(64, 4), 0, stream>>>(Abf, wfcT, bfcf, flags, d_out);
}

// Round 5
// 778.060 us; speedup vs baseline: 2.4022x; 2.4022x over previous
//
#include <hip/hip_runtime.h>
#include <hip/hip_bf16.h>

#define NNODES 100000
#define NEDGES 1600000
#define DF 128
#define NC 40

typedef __bf16 bf16x8 __attribute__((ext_vector_type(8)));
typedef float f32x4 __attribute__((ext_vector_type(4)));

__device__ __forceinline__ unsigned short f2bf(float f) {
    unsigned int u = __builtin_bit_cast(unsigned int, f);
    u = (u + 0x7FFFu + ((u >> 16) & 1u)) >> 16;   // RNE
    return (unsigned short)u;
}
__device__ __forceinline__ float bf2f(unsigned short s) {
    unsigned int u = ((unsigned int)s) << 16;
    return __builtin_bit_cast(float, u);
}

// ---------------- dtype detection (flags[0]: ei is int64; flags[1]: floats are bf16)
__global__ void k_detect(const unsigned int* __restrict__ ei32,
                         const unsigned int* __restrict__ x32,
                         int* __restrict__ flags) {
    __shared__ unsigned int rOr[256];
    __shared__ int rCnt[256];
    unsigned int o = 0; int c = 0;
    for (int i = threadIdx.x; i < 1024; i += 256) o |= ei32[2 * i + 1];
    for (int i = threadIdx.x; i < 4096; i += 256) {
        unsigned int e = (x32[i] >> 7) & 0xFFu;
        c += (e >= 100u && e <= 140u) ? 1 : 0;
    }
    rOr[threadIdx.x] = o; rCnt[threadIdx.x] = c;
    __syncthreads();
    for (int s = 128; s; s >>= 1) {
        if ((int)threadIdx.x < s) {
            rOr[threadIdx.x] |= rOr[threadIdx.x + s];
            rCnt[threadIdx.x] += rCnt[threadIdx.x + s];
        }
        __syncthreads();
    }
    if (threadIdx.x == 0) {
        flags[0] = (rOr[0] == 0u) ? 1 : 0;
        flags[1] = (rCnt[0] > 2457) ? 1 : 0;
    }
}

// ---------------- edge_index -> compact int32
__global__ __launch_bounds__(256) void k_cvt_idx(const void* __restrict__ ei,
                                                 const int* __restrict__ flags,
                                                 int* __restrict__ out, int n) {
    int i = blockIdx.x * 256 + threadIdx.x;
    if (i >= n) return;
    if (flags[0])
        out[i] = (int)((const long long*)ei)[i];
    else
        out[i] = ((const int*)ei)[i];
}

// ---------------- features -> canonical bf16
__global__ __launch_bounds__(256) void k_cvt_feat(const void* __restrict__ src,
                                                  const int* __restrict__ flags,
                                                  unsigned short* __restrict__ dst, int n) {
    int i = blockIdx.x * 256 + threadIdx.x;
    if (i >= n) return;
    dst[i] = flags[1] ? ((const unsigned short*)src)[i]
                      : f2bf(((const float*)src)[i]);
}

// ---------------- bias -> canonical fp32
__global__ void k_cvt_bias(const void* __restrict__ src,
                           const int* __restrict__ flags,
                           float* __restrict__ dst, int n) {
    int i = blockIdx.x * 256 + threadIdx.x;
    if (i >= n) return;
    dst[i] = flags[1] ? bf2f(((const unsigned short*)src)[i])
                      : ((const float*)src)[i];
}

// ---------------- weight transpose -> canonical bf16: dst[n*K+k] = src[k*N+n]
__global__ void k_transpose(const void* __restrict__ src,
                            const int* __restrict__ flags,
                            unsigned short* __restrict__ dst, int K, int N) {
    int idx = blockIdx.x * 256 + threadIdx.x;
    if (idx >= K * N) return;
    int k = idx / N, n = idx - k * N;
    unsigned short v = flags[1] ? ((const unsigned short*)src)[idx]
                                : f2bf(((const float*)src)[idx]);
    dst[n * K + k] = v;
}

// ================= CSR build =================
// deg histogram over dst
__global__ __launch_bounds__(256) void k_hist(const int* __restrict__ dst,
                                              int* __restrict__ deg) {
    int e = blockIdx.x * 256 + threadIdx.x;
    if (e < NEDGES) atomicAdd(&deg[dst[e]], 1);
}

// block-level inclusive scan: 1024 elems/block (256 thr x 4)
__global__ __launch_bounds__(256) void k_scan1(const int* __restrict__ deg,
                                               int* __restrict__ incl,
                                               int* __restrict__ bsum, int n) {
    __shared__ int sh[256];
    int b0 = blockIdx.x * 1024;
    int t = threadIdx.x;
    int v[4]; int s = 0;
#pragma unroll
    for (int k = 0; k < 4; k++) {
        int i = b0 + t * 4 + k;
        v[k] = (i < n) ? deg[i] : 0;
        s += v[k];
    }
    sh[t] = s;
    __syncthreads();
    for (int off = 1; off < 256; off <<= 1) {
        int x = (t >= off) ? sh[t - off] : 0;
        __syncthreads();
        sh[t] += x;
        __syncthreads();
    }
    int run = sh[t] - s;    // exclusive prefix of this thread within block
#pragma unroll
    for (int k = 0; k < 4; k++) {
        run += v[k];
        int i = b0 + t * 4 + k;
        if (i < n) incl[i] = run;
    }
    if (t == 255) bsum[blockIdx.x] = sh[255];
}

// single-block exclusive scan of block sums (nb <= 128)
__global__ __launch_bounds__(128) void k_scan2(int* __restrict__ bsum, int nb) {
    __shared__ int sh[128];
    int t = threadIdx.x;
    int orig = (t < nb) ? bsum[t] : 0;
    sh[t] = orig;
    __syncthreads();
    for (int off = 1; off < 128; off <<= 1) {
        int x = (t >= off) ? sh[t - off] : 0;
        __syncthreads();
        sh[t] += x;
        __syncthreads();
    }
    if (t < nb) bsum[t] = sh[t] - orig;   // exclusive
}

// rowptr[i+1] = incl[i] + bsum[i/1024]; rowptr[0] = 0
__global__ __launch_bounds__(256) void k_scan3(const int* __restrict__ incl,
                                               const int* __restrict__ bsum,
                                               int* __restrict__ rowptr, int n) {
    int i = blockIdx.x * 256 + threadIdx.x;
    if (i < n) rowptr[i + 1] = incl[i] + bsum[i >> 10];
    if (i == 0) rowptr[0] = 0;
}

// fill perm: for each edge, perm[rowptr[d] + cursor[d]++] = src
__global__ __launch_bounds__(256) void k_fill(const int* __restrict__ src,
                                              const int* __restrict__ dst,
                                              const int* __restrict__ rowptr,
                                              int* __restrict__ cursor,
                                              int* __restrict__ perm) {
    int e = blockIdx.x * 256 + threadIdx.x;
    if (e >= NEDGES) return;
    int d = dst[e];
    int pos = rowptr[d] + atomicAdd(&cursor[d], 1);
    perm[pos] = src[e];
}

// ================= gather aggregation =================
// out[i] = bf16( bf2f(x[i]) + sum_{j in CSR[i]} bf2f(feat[perm[j]]) )
// one wave per node; lane holds feature pair (2 bf16 = 1 uint). 4-edge unroll.
__global__ __launch_bounds__(256) void k_gather(const unsigned short* __restrict__ feat,
                                                const unsigned short* __restrict__ x,
                                                const int* __restrict__ rowptr,
                                                const int* __restrict__ perm,
                                                unsigned short* __restrict__ out) {
    int wave = threadIdx.x >> 6, lane = threadIdx.x & 63;
    int i = blockIdx.x * 4 + wave;        // NNODES = 25000*4 exactly
    const unsigned int* F = (const unsigned int*)feat;
    unsigned int xv = ((const unsigned int*)x)[i * 64 + lane];
    float accL = bf2f((unsigned short)(xv & 0xFFFFu));
    float accH = bf2f((unsigned short)(xv >> 16));
    int jb = rowptr[i], je = rowptr[i + 1];
    int j = jb;
    for (; j + 4 <= je; j += 4) {
        int s0 = perm[j], s1 = perm[j + 1], s2 = perm[j + 2], s3 = perm[j + 3];
        unsigned int v0 = F[s0 * 64 + lane];
        unsigned int v1 = F[s1 * 64 + lane];
        unsigned int v2 = F[s2 * 64 + lane];
        unsigned int v3 = F[s3 * 64 + lane];
        accL += bf2f((unsigned short)(v0 & 0xFFFFu)) + bf2f((unsigned short)(v1 & 0xFFFFu))
              + bf2f((unsigned short)(v2 & 0xFFFFu)) + bf2f((unsigned short)(v3 & 0xFFFFu));
        accH += bf2f((unsigned short)(v0 >> 16)) + bf2f((unsigned short)(v1 >> 16))
              + bf2f((unsigned short)(v2 >> 16)) + bf2f((unsigned short)(v3 >> 16));
    }
    for (; j < je; j++) {
        unsigned int v = F[perm[j] * 64 + lane];
        accL += bf2f((unsigned short)(v & 0xFFFFu));
        accH += bf2f((unsigned short)(v >> 16));
    }
    unsigned int r = ((unsigned int)f2bf(accH) << 16) | f2bf(accL);
    ((unsigned int*)out)[i * 64 + lane] = r;
}

// ---------------- MFMA GEMM: C[M x 128] = act(A @ W + bias), bf16 in/out, fp32 acc.
// Layouts (m89/m91): A[m=lane&15][k=quad*8+j]; B[k=quad*8+j][n=lane&15];
// D: col=lane&15, row=quad*4+reg.
__global__ __launch_bounds__(256) void k_gemm128(const unsigned short* __restrict__ A,
                                                 const unsigned short* __restrict__ WT,
                                                 const float* __restrict__ bias,
                                                 unsigned short* __restrict__ out,
                                                 int M, int relu) {
    int tid = threadIdx.x;
    int wave = tid >> 6, lane = tid & 63;
    int m = lane & 15, quad = lane >> 4;
    int tile = blockIdx.x * 4 + wave;
    int r0 = tile * 16;
    if (r0 >= M) return;

    const unsigned short* Ab = A + (r0 + m) * DF + quad * 8;
    bf16x8 a[4];
#pragma unroll
    for (int ks = 0; ks < 4; ks++) a[ks] = *(const bf16x8*)(Ab + ks * 32);

    f32x4 acc[8];
#pragma unroll
    for (int nt = 0; nt < 8; nt++) acc[nt] = (f32x4){0.f, 0.f, 0.f, 0.f};

#pragma unroll
    for (int nt = 0; nt < 8; nt++) {
        const unsigned short* Bb = WT + (nt * 16 + m) * DF + quad * 8;
#pragma unroll
        for (int ks = 0; ks < 4; ks++) {
            bf16x8 b = *(const bf16x8*)(Bb + ks * 32);
            acc[nt] = __builtin_amdgcn_mfma_f32_16x16x32_bf16(a[ks], b, acc[nt], 0, 0, 0);
        }
    }

#pragma unroll
    for (int nt = 0; nt < 8; nt++) {
        int col = nt * 16 + m;
        float bv = bias[col];
#pragma unroll
        for (int reg = 0; reg < 4; reg++) {
            int row = r0 + quad * 4 + reg;
            float v = acc[nt][reg] + bv;
            if (relu && v < 0.f) v = 0.f;
            out[row * DF + col] = f2bf(v);
        }
    }
}

// ---------------- fc (128 -> 40) + log_softmax fused. One wave per row.
__global__ __launch_bounds__(256) void k_fc_lsm(const unsigned short* __restrict__ H,
                                                const unsigned short* __restrict__ WfcT,
                                                const float* __restrict__ bfc,
                                                const int* __restrict__ flags,
                                                void* __restrict__ out) {
    int col = threadIdx.x;                       // 0..63
    int row = blockIdx.x * 4 + threadIdx.y;      // 25000 * 4 = 100000 exactly
    bool act = col < NC;
    const unsigned short* h = H + row * DF;
    const unsigned short* w = WfcT + (act ? col : 0) * DF;
    float acc = act ? bfc[col] : 0.f;
#pragma unroll 8
    for (int k = 0; k < DF; k++) acc += bf2f(h[k]) * bf2f(w[k]);

    float v = act ? acc : -1e30f;
#pragma unroll
    for (int off = 32; off; off >>= 1) {
        float o = __shfl_xor(v, off, 64);
        v = v > o ? v : o;
    }
    float mx = v;
    float e = act ? __expf(acc - mx) : 0.f;
#pragma unroll
    for (int off = 32; off; off >>= 1) e += __shfl_xor(e, off, 64);
    if (act) {
        float r = acc - mx - __logf(e);
        if (flags[1])
            ((unsigned short*)out)[row * NC + col] = f2bf(r);
        else
            ((float*)out)[row * NC + col] = r;
    }
}

extern "C" void kernel_launch(void* const* d_in, const int* in_sizes, int n_in,
                              void* d_out, int out_size, void* d_ws, size_t ws_size,
                              hipStream_t stream) {
    const void* x   = d_in[0];
    const void* ei  = d_in[1];
    const void* w1a = d_in[2];
    const void* b1a = d_in[3];
    const void* w1b = d_in[4];
    const void* b1b = d_in[5];
    const void* w2a = d_in[6];
    const void* b2a = d_in[7];
    const void* w2b = d_in[8];
    const void* b2b = d_in[9];
    const void* wfc = d_in[10];
    const void* bfc = d_in[11];

    char* ws = (char*)d_ws;
    size_t off = 0;
    auto alloc = [&](size_t bytes) {
        void* p = ws + off;
        off += (bytes + 255) & ~(size_t)255;
        return p;
    };
    unsigned short* xc    = (unsigned short*)alloc((size_t)NNODES * DF * 2);
    unsigned short* h1    = (unsigned short*)alloc((size_t)NNODES * DF * 2);
    unsigned short* Abf   = (unsigned short*)alloc((size_t)NNODES * DF * 2);
    unsigned short* T1    = (unsigned short*)alloc((size_t)NNODES * DF * 2);
    int*            idx   = (int*)alloc((size_t)2 * NEDGES * 4);
    int*            perm  = (int*)alloc((size_t)NEDGES * 4);
    int*            rowptr= (int*)alloc((size_t)(NNODES + 1) * 4);
    int*            deg   = (int*)alloc((size_t)NNODES * 4);
    int*            incl  = (int*)alloc((size_t)NNODES * 4);
    int*            cursor= (int*)alloc((size_t)NNODES * 4);
    int*            bsum  = (int*)alloc(128 * 4);
    int*            flags = (int*)alloc(256);
    unsigned short* w1aT  = (unsigned short*)alloc(128 * 128 * 2);
    unsigned short* w1bT  = (unsigned short*)alloc(128 * 128 * 2);
    unsigned short* w2aT  = (unsigned short*)alloc(128 * 128 * 2);
    unsigned short* w2bT  = (unsigned short*)alloc(128 * 128 * 2);
    unsigned short* wfcT  = (unsigned short*)alloc(NC * 128 * 2);
    float*          b1af  = (float*)alloc(128 * 4);
    float*          b1bf  = (float*)alloc(128 * 4);
    float*          b2af  = (float*)alloc(128 * 4);
    float*          b2bf  = (float*)alloc(128 * 4);
    float*          bfcf  = (float*)alloc(NC * 4);

    // ---- dtype detection + canonicalization
    k_detect<<<1, 256, 0, stream>>>((const unsigned int*)ei, (const unsigned int*)x, flags);
    k_cvt_idx<<<(2 * NEDGES + 255) / 256, 256, 0, stream>>>(ei, flags, idx, 2 * NEDGES);
    k_cvt_feat<<<(NNODES * DF + 255) / 256, 256, 0, stream>>>(x, flags, xc, NNODES * DF);
    const int* src = idx;
    const int* dst = idx + NEDGES;

    int wblk = (128 * 128 + 255) / 256;
    k_transpose<<<wblk, 256, 0, stream>>>(w1a, flags, w1aT, 128, 128);
    k_transpose<<<wblk, 256, 0, stream>>>(w1b, flags, w1bT, 128, 128);
    k_transpose<<<wblk, 256, 0, stream>>>(w2a, flags, w2aT, 128, 128);
    k_transpose<<<wblk, 256, 0, stream>>>(w2b, flags, w2bT, 128, 128);
    k_transpose<<<(128 * NC + 255) / 256, 256, 0, stream>>>(wfc, flags, wfcT, 128, NC);
    k_cvt_bias<<<1, 256, 0, stream>>>(b1a, flags, b1af, 128);
    k_cvt_bias<<<1, 256, 0, stream>>>(b1b, flags, b1bf, 128);
    k_cvt_bias<<<1, 256, 0, stream>>>(b2a, flags, b2af, 128);
    k_cvt_bias<<<1, 256, 0, stream>>>(b2b, flags, b2bf, 128);
    k_cvt_bias<<<1, 256, 0, stream>>>(bfc, flags, bfcf, NC);

    // ---- CSR build (once; shared by both layers)
    hipMemsetAsync(deg, 0, (size_t)NNODES * 4, stream);
    hipMemsetAsync(cursor, 0, (size_t)NNODES * 4, stream);
    k_hist<<<(NEDGES + 255) / 256, 256, 0, stream>>>(dst, deg);
    int nscan = (NNODES + 1023) / 1024;                       // 98
    k_scan1<<<nscan, 256, 0, stream>>>(deg, incl, bsum, NNODES);
    k_scan2<<<1, 128, 0, stream>>>(bsum, nscan);
    k_scan3<<<(NNODES + 255) / 256, 256, 0, stream>>>(incl, bsum, rowptr, NNODES);
    k_fill<<<(NEDGES + 255) / 256, 256, 0, stream>>>(src, dst, rowptr, cursor, perm);

    const int gemmGrid = (NNODES / 16 + 3) / 4;               // 6250 tiles / 4 waves
    const int gatherGrid = NNODES / 4;                        // 25000

    // ---- layer 1
    k_gather<<<gatherGrid, 256, 0, stream>>>(xc, xc, rowptr, perm, Abf);
    k_gemm128<<<gemmGrid, 256, 0, stream>>>(Abf, w1aT, b1af, T1, NNODES, 1);
    k_gemm128<<<gemmGrid, 256, 0, stream>>>(T1, w1bT, b1bf, h1, NNODES, 1);

    // ---- layer 2
    k_gather<<<gatherGrid, 256, 0, stream>>>(h1, h1, rowptr, perm, Abf);
    k_gemm128<<<gemmGrid, 256, 0, stream>>>(Abf, w2aT, b2af, T1, NNODES, 1);
    k_gemm128<<<gemmGrid, 256, 0, stream>>>(T1, w2bT, b2bf, Abf, NNODES, 1);  // H2

    // ---- fc + log_softmax
    k_fc_lsm<<<NNODES / 4, dim3(64, 4), 0, stream>>>(Abf, wfcT, bfcf, flags, d_out);
}

// Round 6
// 606.523 us; speedup vs baseline: 3.0816x; 1.2828x over previous
//
#include <hip/hip_runtime.h>
#include <hip/hip_bf16.h>

#define NNODES 100000
#define NEDGES 1600000
#define DF 128
#define NC 40
#define NCP 48   // padded fc cols (3 x 16)

typedef __bf16 bf16x8 __attribute__((ext_vector_type(8)));
typedef float f32x4 __attribute__((ext_vector_type(4)));

__device__ __forceinline__ unsigned short f2bf(float f) {
    unsigned int u = __builtin_bit_cast(unsigned int, f);
    u = (u + 0x7FFFu + ((u >> 16) & 1u)) >> 16;   // RNE
    return (unsigned short)u;
}
__device__ __forceinline__ float bf2f(unsigned short s) {
    unsigned int u = ((unsigned int)s) << 16;
    return __builtin_bit_cast(float, u);
}

// ---------------- dtype detection (flags[0]: ei is int64; flags[1]: floats are bf16)
__global__ void k_detect(const unsigned int* __restrict__ ei32,
                         const unsigned int* __restrict__ x32,
                         int* __restrict__ flags) {
    __shared__ unsigned int rOr[256];
    __shared__ int rCnt[256];
    unsigned int o = 0; int c = 0;
    for (int i = threadIdx.x; i < 1024; i += 256) o |= ei32[2 * i + 1];
    for (int i = threadIdx.x; i < 4096; i += 256) {
        unsigned int e = (x32[i] >> 7) & 0xFFu;
        c += (e >= 100u && e <= 140u) ? 1 : 0;
    }
    rOr[threadIdx.x] = o; rCnt[threadIdx.x] = c;
    __syncthreads();
    for (int s = 128; s; s >>= 1) {
        if ((int)threadIdx.x < s) {
            rOr[threadIdx.x] |= rOr[threadIdx.x + s];
            rCnt[threadIdx.x] += rCnt[threadIdx.x + s];
        }
        __syncthreads();
    }
    if (threadIdx.x == 0) {
        flags[0] = (rOr[0] == 0u) ? 1 : 0;
        flags[1] = (rCnt[0] > 2457) ? 1 : 0;
    }
}

// ---------------- edge_index -> compact int32
__global__ __launch_bounds__(256) void k_cvt_idx(const void* __restrict__ ei,
                                                 const int* __restrict__ flags,
                                                 int* __restrict__ out, int n) {
    int i = blockIdx.x * 256 + threadIdx.x;
    if (i >= n) return;
    if (flags[0])
        out[i] = (int)((const long long*)ei)[i];
    else
        out[i] = ((const int*)ei)[i];
}

// ---------------- features -> canonical bf16
__global__ __launch_bounds__(256) void k_cvt_feat(const void* __restrict__ src,
                                                  const int* __restrict__ flags,
                                                  unsigned short* __restrict__ dst, int n) {
    int i = blockIdx.x * 256 + threadIdx.x;
    if (i >= n) return;
    dst[i] = flags[1] ? ((const unsigned short*)src)[i]
                      : f2bf(((const float*)src)[i]);
}

// ---------------- all weights (transposed, bf16) + all biases (fp32) in ONE launch.
// wAll layout (ushort): [0)w1aT [16384)w1bT [32768)w2aT [49152)w2bT [65536)wfcT(48x128, rows 40+ zero)
// bAll layout (float):  [0)b1a [128)b1b [256)b2a [384)b2b [512)bfc(40)
__global__ __launch_bounds__(256) void k_wprep(const void* w1a, const void* w1b,
                                               const void* w2a, const void* w2b,
                                               const void* wfc,
                                               const void* b1a, const void* b1b,
                                               const void* b2a, const void* b2b,
                                               const void* bfc,
                                               const int* __restrict__ flags,
                                               unsigned short* __restrict__ wAll,
                                               float* __restrict__ bAll) {
    int idx = blockIdx.x * 256 + threadIdx.x;
    int bf = flags[1];
    auto ldf = [&](const void* p, int i) -> float {
        return bf ? bf2f(((const unsigned short*)p)[i]) : ((const float*)p)[i];
    };
    if (idx < 65536) {                       // 4 square transposes: dst[n*128+k]=src[k*128+n]
        int wi = idx >> 14, r = idx & 16383;
        int n = r >> 7, k = r & 127;
        const void* s = (wi == 0) ? w1a : (wi == 1) ? w1b : (wi == 2) ? w2a : w2b;
        wAll[idx] = f2bf(ldf(s, k * 128 + n));
    } else if (idx < 65536 + NCP * 128) {    // wfc transpose with zero pad
        int r = idx - 65536;
        int n = r >> 7, k = r & 127;
        wAll[idx] = (n < NC) ? f2bf(ldf(wfc, k * NC + n)) : (unsigned short)0;
    } else if (idx < 65536 + NCP * 128 + 512 + NC) {
        int r = idx - (65536 + NCP * 128);
        const void* s; int i;
        if (r < 128)      { s = b1a; i = r; }
        else if (r < 256) { s = b1b; i = r - 128; }
        else if (r < 384) { s = b2a; i = r - 256; }
        else if (r < 512) { s = b2b; i = r - 384; }
        else              { s = bfc; i = r - 512; }
        bAll[r] = ldf(s, i);
    }
}

// ================= CSR build =================
__global__ __launch_bounds__(256) void k_hist(const int* __restrict__ dst,
                                              int* __restrict__ deg) {
    int e = blockIdx.x * 256 + threadIdx.x;
    if (e < NEDGES) atomicAdd(&deg[dst[e]], 1);
}

__global__ __launch_bounds__(256) void k_scan1(const int* __restrict__ deg,
                                               int* __restrict__ incl,
                                               int* __restrict__ bsum, int n) {
    __shared__ int sh[256];
    int b0 = blockIdx.x * 1024;
    int t = threadIdx.x;
    int v[4]; int s = 0;
#pragma unroll
    for (int k = 0; k < 4; k++) {
        int i = b0 + t * 4 + k;
        v[k] = (i < n) ? deg[i] : 0;
        s += v[k];
    }
    sh[t] = s;
    __syncthreads();
    for (int off = 1; off < 256; off <<= 1) {
        int x = (t >= off) ? sh[t - off] : 0;
        __syncthreads();
        sh[t] += x;
        __syncthreads();
    }
    int run = sh[t] - s;
#pragma unroll
    for (int k = 0; k < 4; k++) {
        run += v[k];
        int i = b0 + t * 4 + k;
        if (i < n) incl[i] = run;
    }
    if (t == 255) bsum[blockIdx.x] = sh[255];
}

__global__ __launch_bounds__(128) void k_scan2(int* __restrict__ bsum, int nb) {
    __shared__ int sh[128];
    int t = threadIdx.x;
    int orig = (t < nb) ? bsum[t] : 0;
    sh[t] = orig;
    __syncthreads();
    for (int off = 1; off < 128; off <<= 1) {
        int x = (t >= off) ? sh[t - off] : 0;
        __syncthreads();
        sh[t] += x;
        __syncthreads();
    }
    if (t < nb) bsum[t] = sh[t] - orig;
}

__global__ __launch_bounds__(256) void k_scan3(const int* __restrict__ incl,
                                               const int* __restrict__ bsum,
                                               int* __restrict__ rowptr, int n) {
    int i = blockIdx.x * 256 + threadIdx.x;
    if (i < n) rowptr[i + 1] = incl[i] + bsum[i >> 10];
    if (i == 0) rowptr[0] = 0;
}

__global__ __launch_bounds__(256) void k_fill(const int* __restrict__ src,
                                              const int* __restrict__ dst,
                                              const int* __restrict__ rowptr,
                                              int* __restrict__ cursor,
                                              int* __restrict__ perm) {
    int e = blockIdx.x * 256 + threadIdx.x;
    if (e >= NEDGES) return;
    int d = dst[e];
    int pos = rowptr[d] + atomicAdd(&cursor[d], 1);
    perm[pos] = src[e];
}

// ================= gather aggregation =================
__global__ __launch_bounds__(256) void k_gather(const unsigned short* __restrict__ feat,
                                                const unsigned short* __restrict__ x,
                                                const int* __restrict__ rowptr,
                                                const int* __restrict__ perm,
                                                unsigned short* __restrict__ out) {
    int wave = threadIdx.x >> 6, lane = threadIdx.x & 63;
    int i = blockIdx.x * 4 + wave;        // NNODES = 25000*4 exactly
    const unsigned int* F = (const unsigned int*)feat;
    unsigned int xv = ((const unsigned int*)x)[i * 64 + lane];
    float accL = bf2f((unsigned short)(xv & 0xFFFFu));
    float accH = bf2f((unsigned short)(xv >> 16));
    int jb = rowptr[i], je = rowptr[i + 1];
    int j = jb;
    for (; j + 4 <= je; j += 4) {
        int s0 = perm[j], s1 = perm[j + 1], s2 = perm[j + 2], s3 = perm[j + 3];
        unsigned int v0 = F[s0 * 64 + lane];
        unsigned int v1 = F[s1 * 64 + lane];
        unsigned int v2 = F[s2 * 64 + lane];
        unsigned int v3 = F[s3 * 64 + lane];
        accL += bf2f((unsigned short)(v0 & 0xFFFFu)) + bf2f((unsigned short)(v1 & 0xFFFFu))
              + bf2f((unsigned short)(v2 & 0xFFFFu)) + bf2f((unsigned short)(v3 & 0xFFFFu));
        accH += bf2f((unsigned short)(v0 >> 16)) + bf2f((unsigned short)(v1 >> 16))
              + bf2f((unsigned short)(v2 >> 16)) + bf2f((unsigned short)(v3 >> 16));
    }
    for (; j < je; j++) {
        unsigned int v = F[perm[j] * 64 + lane];
        accL += bf2f((unsigned short)(v & 0xFFFFu));
        accH += bf2f((unsigned short)(v >> 16));
    }
    unsigned int r = ((unsigned int)f2bf(accH) << 16) | f2bf(accL);
    ((unsigned int*)out)[i * 64 + lane] = r;
}

// ---------------- MFMA GEMM: C[M x 128] = relu(A @ W + bias), bf16 in/out, fp32 acc.
// Layouts (m89/m91): A[m=lane&15][k=quad*8+j]; B[k=quad*8+j][n=lane&15];
// D: col=lane&15, row=quad*4+reg.
__global__ __launch_bounds__(256) void k_gemm128(const unsigned short* __restrict__ A,
                                                 const unsigned short* __restrict__ WT,
                                                 const float* __restrict__ bias,
                                                 unsigned short* __restrict__ out,
                                                 int M) {
    int tid = threadIdx.x;
    int wave = tid >> 6, lane = tid & 63;
    int m = lane & 15, quad = lane >> 4;
    int tile = blockIdx.x * 4 + wave;
    int r0 = tile * 16;
    if (r0 >= M) return;

    const unsigned short* Ab = A + (r0 + m) * DF + quad * 8;
    bf16x8 a[4];
#pragma unroll
    for (int ks = 0; ks < 4; ks++) a[ks] = *(const bf16x8*)(Ab + ks * 32);

    f32x4 acc[8];
#pragma unroll
    for (int nt = 0; nt < 8; nt++) acc[nt] = (f32x4){0.f, 0.f, 0.f, 0.f};

#pragma unroll
    for (int nt = 0; nt < 8; nt++) {
        const unsigned short* Bb = WT + (nt * 16 + m) * DF + quad * 8;
#pragma unroll
        for (int ks = 0; ks < 4; ks++) {
            bf16x8 b = *(const bf16x8*)(Bb + ks * 32);
            acc[nt] = __builtin_amdgcn_mfma_f32_16x16x32_bf16(a[ks], b, acc[nt], 0, 0, 0);
        }
    }

#pragma unroll
    for (int nt = 0; nt < 8; nt++) {
        int col = nt * 16 + m;
        float bv = bias[col];
#pragma unroll
        for (int reg = 0; reg < 4; reg++) {
            int row = r0 + quad * 4 + reg;
            float v = acc[nt][reg] + bv;
            if (v < 0.f) v = 0.f;
            out[row * DF + col] = f2bf(v);
        }
    }
}

// ---------------- fc (128 -> 40, padded 48) via MFMA + fused log_softmax epilogue.
// Wave tile: 16 rows x 48 cols (3 n-tiles). Row r0+quad*4+reg lives in one
// 16-lane quad -> log-softmax reduction = shfl_xor width 16. Cols >= 40 masked.
__global__ __launch_bounds__(256) void k_fc_lsm(const unsigned short* __restrict__ A,
                                                const unsigned short* __restrict__ WfcT,
                                                const float* __restrict__ bfc,
                                                const int* __restrict__ flags,
                                                void* __restrict__ out) {
    int tid = threadIdx.x;
    int wave = tid >> 6, lane = tid & 63;
    int m = lane & 15, quad = lane >> 4;
    int tile = blockIdx.x * 4 + wave;
    int r0 = tile * 16;
    if (r0 >= NNODES) return;
    bool valid2 = (m < 8);                  // n-tile 2 covers cols 32..47; 40+ invalid
    int obf = flags[1];

    const unsigned short* Ab = A + (r0 + m) * DF + quad * 8;
    bf16x8 a[4];
#pragma unroll
    for (int ks = 0; ks < 4; ks++) a[ks] = *(const bf16x8*)(Ab + ks * 32);

    f32x4 acc[3];
#pragma unroll
    for (int nt = 0; nt < 3; nt++) acc[nt] = (f32x4){0.f, 0.f, 0.f, 0.f};

#pragma unroll
    for (int nt = 0; nt < 3; nt++) {
        const unsigned short* Bb = WfcT + (nt * 16 + m) * DF + quad * 8;
#pragma unroll
        for (int ks = 0; ks < 4; ks++) {
            bf16x8 b = *(const bf16x8*)(Bb + ks * 32);
            acc[nt] = __builtin_amdgcn_mfma_f32_16x16x32_bf16(a[ks], b, acc[nt], 0, 0, 0);
        }
    }

    float bv0 = bfc[m], bv1 = bfc[16 + m];
    float bv2 = valid2 ? bfc[32 + m] : 0.f;

#pragma unroll
    for (int reg = 0; reg < 4; reg++) {
        float v0 = acc[0][reg] + bv0;
        float v1 = acc[1][reg] + bv1;
        float v2 = valid2 ? (acc[2][reg] + bv2) : -3.0e38f;
        float mx = fmaxf(fmaxf(v0, v1), v2);
#pragma unroll
        for (int off = 1; off < 16; off <<= 1) mx = fmaxf(mx, __shfl_xor(mx, off, 16));
        float e = __expf(v0 - mx) + __expf(v1 - mx) + (valid2 ? __expf(v2 - mx) : 0.f);
#pragma unroll
        for (int off = 1; off < 16; off <<= 1) e += __shfl_xor(e, off, 16);
        float l = mx + __logf(e);
        int row = r0 + quad * 4 + reg;
        if (obf) {
            unsigned short* o = (unsigned short*)out + row * NC;
            o[m] = f2bf(v0 - l);
            o[16 + m] = f2bf(v1 - l);
            if (valid2) o[32 + m] = f2bf(v2 - l);
        } else {
            float* o = (float*)out + row * NC;
            o[m] = v0 - l;
            o[16 + m] = v1 - l;
            if (valid2) o[32 + m] = v2 - l;
        }
    }
}

extern "C" void kernel_launch(void* const* d_in, const int* in_sizes, int n_in,
                              void* d_out, int out_size, void* d_ws, size_t ws_size,
                              hipStream_t stream) {
    const void* x   = d_in[0];
    const void* ei  = d_in[1];
    const void* w1a = d_in[2];
    const void* b1a = d_in[3];
    const void* w1b = d_in[4];
    const void* b1b = d_in[5];
    const void* w2a = d_in[6];
    const void* b2a = d_in[7];
    const void* w2b = d_in[8];
    const void* b2b = d_in[9];
    const void* wfc = d_in[10];
    const void* bfc = d_in[11];

    char* ws = (char*)d_ws;
    size_t off = 0;
    auto alloc = [&](size_t bytes) {
        void* p = ws + off;
        off += (bytes + 255) & ~(size_t)255;
        return p;
    };
    unsigned short* xc    = (unsigned short*)alloc((size_t)NNODES * DF * 2);
    unsigned short* h1    = (unsigned short*)alloc((size_t)NNODES * DF * 2);
    unsigned short* Abf   = (unsigned short*)alloc((size_t)NNODES * DF * 2);
    unsigned short* T1    = (unsigned short*)alloc((size_t)NNODES * DF * 2);
    int*            idx   = (int*)alloc((size_t)2 * NEDGES * 4);
    int*            perm  = (int*)alloc((size_t)NEDGES * 4);
    int*            rowptr= (int*)alloc((size_t)(NNODES + 1) * 4);
    int*            deg   = (int*)alloc((size_t)NNODES * 4);
    int*            incl  = (int*)alloc((size_t)NNODES * 4);
    int*            cursor= (int*)alloc((size_t)NNODES * 4);
    int*            bsum  = (int*)alloc(128 * 4);
    int*            flags = (int*)alloc(256);
    unsigned short* wAll  = (unsigned short*)alloc((4 * 16384 + NCP * 128) * 2);
    float*          bAll  = (float*)alloc((512 + NC) * 4);

    unsigned short* w1aT = wAll;
    unsigned short* w1bT = wAll + 16384;
    unsigned short* w2aT = wAll + 32768;
    unsigned short* w2bT = wAll + 49152;
    unsigned short* wfcT = wAll + 65536;
    float* b1af = bAll;
    float* b1bf = bAll + 128;
    float* b2af = bAll + 256;
    float* b2bf = bAll + 384;
    float* bfcf = bAll + 512;

    // ---- dtype detection + canonicalization
    k_detect<<<1, 256, 0, stream>>>((const unsigned int*)ei, (const unsigned int*)x, flags);
    k_cvt_idx<<<(2 * NEDGES + 255) / 256, 256, 0, stream>>>(ei, flags, idx, 2 * NEDGES);
    k_cvt_feat<<<(NNODES * DF + 255) / 256, 256, 0, stream>>>(x, flags, xc, NNODES * DF);
    const int* src = idx;
    const int* dst = idx + NEDGES;

    int wprepN = 4 * 16384 + NCP * 128 + 512 + NC;
    k_wprep<<<(wprepN + 255) / 256, 256, 0, stream>>>(w1a, w1b, w2a, w2b, wfc,
                                                      b1a, b1b, b2a, b2b, bfc,
                                                      flags, wAll, bAll);

    // ---- CSR build (once; shared by both layers)
    hipMemsetAsync(deg, 0, (size_t)NNODES * 4, stream);
    hipMemsetAsync(cursor, 0, (size_t)NNODES * 4, stream);
    k_hist<<<(NEDGES + 255) / 256, 256, 0, stream>>>(dst, deg);
    int nscan = (NNODES + 1023) / 1024;                       // 98
    k_scan1<<<nscan, 256, 0, stream>>>(deg, incl, bsum, NNODES);
    k_scan2<<<1, 128, 0, stream>>>(bsum, nscan);
    k_scan3<<<(NNODES + 255) / 256, 256, 0, stream>>>(incl, bsum, rowptr, NNODES);
    k_fill<<<(NEDGES + 255) / 256, 256, 0, stream>>>(src, dst, rowptr, cursor, perm);

    const int gemmGrid = (NNODES / 16 + 3) / 4;               // 1563
    const int gatherGrid = NNODES / 4;                        // 25000

    // ---- layer 1
    k_gather<<<gatherGrid, 256, 0, stream>>>(xc, xc, rowptr, perm, Abf);
    k_gemm128<<<gemmGrid, 256, 0, stream>>>(Abf, w1aT, b1af, T1, NNODES);
    k_gemm128<<<gemmGrid, 256, 0, stream>>>(T1, w1bT, b1bf, h1, NNODES);

    // ---- layer 2
    k_gather<<<gatherGrid, 256, 0, stream>>>(h1, h1, rowptr, perm, Abf);
    k_gemm128<<<gemmGrid, 256, 0, stream>>>(Abf, w2aT, b2af, T1, NNODES);
    k_gemm128<<<gemmGrid, 256, 0, stream>>>(T1, w2bT, b2bf, Abf, NNODES);  // H2

    // ---- fc + log_softmax (MFMA, fused)
    k_fc_lsm<<<gemmGrid, 256, 0, stream>>>(Abf, wfcT, bfcf, flags, d_out);
}

// Round 7
// 472.471 us; speedup vs baseline: 3.9560x; 1.2837x over previous
//
#include <hip/hip_runtime.h>
#include <hip/hip_bf16.h>

#define NNODES 100000
#define NEDGES 1600000
#define DF 128
#define NC 40
#define NCP 48          // padded fc cols (3 x 16)
#define NB 196          // CSR bins: dst>>9, 512 nodes/bin
#define CH 4096         // edges per binscatter/bincount block

typedef __bf16 bf16x8 __attribute__((ext_vector_type(8)));
typedef float f32x4 __attribute__((ext_vector_type(4)));

__device__ __forceinline__ unsigned short f2bf(float f) {
    unsigned int u = __builtin_bit_cast(unsigned int, f);
    u = (u + 0x7FFFu + ((u >> 16) & 1u)) >> 16;   // RNE
    return (unsigned short)u;
}
__device__ __forceinline__ float bf2f(unsigned short s) {
    unsigned int u = ((unsigned int)s) << 16;
    return __builtin_bit_cast(float, u);
}

// ---------------- dtype detection (flags[0]: ei is int64; flags[1]: floats are bf16)
__global__ void k_detect(const unsigned int* __restrict__ ei32,
                         const unsigned int* __restrict__ x32,
                         int* __restrict__ flags) {
    __shared__ unsigned int rOr[256];
    __shared__ int rCnt[256];
    unsigned int o = 0; int c = 0;
    for (int i = threadIdx.x; i < 1024; i += 256) o |= ei32[2 * i + 1];
    for (int i = threadIdx.x; i < 4096; i += 256) {
        unsigned int e = (x32[i] >> 7) & 0xFFu;
        c += (e >= 100u && e <= 140u) ? 1 : 0;
    }
    rOr[threadIdx.x] = o; rCnt[threadIdx.x] = c;
    __syncthreads();
    for (int s = 128; s; s >>= 1) {
        if ((int)threadIdx.x < s) {
            rOr[threadIdx.x] |= rOr[threadIdx.x + s];
            rCnt[threadIdx.x] += rCnt[threadIdx.x + s];
        }
        __syncthreads();
    }
    if (threadIdx.x == 0) {
        flags[0] = (rOr[0] == 0u) ? 1 : 0;
        flags[1] = (rCnt[0] > 2457) ? 1 : 0;
    }
}

// ---------------- edge_index -> int2 {src, dst}
__global__ __launch_bounds__(256) void k_cvt_idx(const void* __restrict__ ei,
                                                 const int* __restrict__ flags,
                                                 int2* __restrict__ e2) {
    int e = blockIdx.x * 256 + threadIdx.x;
    if (e >= NEDGES) return;
    int2 v;
    if (flags[0]) {
        v.x = (int)((const long long*)ei)[e];
        v.y = (int)((const long long*)ei)[NEDGES + e];
    } else {
        v.x = ((const int*)ei)[e];
        v.y = ((const int*)ei)[NEDGES + e];
    }
    e2[e] = v;
}

// ---------------- features -> canonical bf16
__global__ __launch_bounds__(256) void k_cvt_feat(const void* __restrict__ src,
                                                  const int* __restrict__ flags,
                                                  unsigned short* __restrict__ dst, int n) {
    int i = blockIdx.x * 256 + threadIdx.x;
    if (i >= n) return;
    dst[i] = flags[1] ? ((const unsigned short*)src)[i]
                      : f2bf(((const float*)src)[i]);
}

// ---------------- all weights (transposed bf16) + biases (fp32) in ONE launch.
__global__ __launch_bounds__(256) void k_wprep(const void* w1a, const void* w1b,
                                               const void* w2a, const void* w2b,
                                               const void* wfc,
                                               const void* b1a, const void* b1b,
                                               const void* b2a, const void* b2b,
                                               const void* bfc,
                                               const int* __restrict__ flags,
                                               unsigned short* __restrict__ wAll,
                                               float* __restrict__ bAll) {
    int idx = blockIdx.x * 256 + threadIdx.x;
    int bf = flags[1];
    auto ldf = [&](const void* p, int i) -> float {
        return bf ? bf2f(((const unsigned short*)p)[i]) : ((const float*)p)[i];
    };
    if (idx < 65536) {                       // 4 square transposes
        int wi = idx >> 14, r = idx & 16383;
        int n = r >> 7, k = r & 127;
        const void* s = (wi == 0) ? w1a : (wi == 1) ? w1b : (wi == 2) ? w2a : w2b;
        wAll[idx] = f2bf(ldf(s, k * 128 + n));
    } else if (idx < 65536 + NCP * 128) {    // wfc transpose, zero pad
        int r = idx - 65536;
        int n = r >> 7, k = r & 127;
        wAll[idx] = (n < NC) ? f2bf(ldf(wfc, k * NC + n)) : (unsigned short)0;
    } else if (idx < 65536 + NCP * 128 + 512 + NC) {
        int r = idx - (65536 + NCP * 128);
        const void* s; int i;
        if (r < 128)      { s = b1a; i = r; }
        else if (r < 256) { s = b1b; i = r - 128; }
        else if (r < 384) { s = b2a; i = r - 256; }
        else if (r < 512) { s = b2b; i = r - 384; }
        else              { s = bfc; i = r - 512; }
        bAll[r] = ldf(s, i);
    }
}

// ================= binned CSR build =================
// bin = dst >> 9 (196 bins). bincount -> binscan -> binscatter -> binfill.
__global__ __launch_bounds__(256) void k_bincount(const int2* __restrict__ e2,
                                                  int* __restrict__ binCnt) {
    __shared__ int l[NB];
    int t = threadIdx.x;
    for (int i = t; i < NB; i += 256) l[i] = 0;
    __syncthreads();
    int base = blockIdx.x * CH;
#pragma unroll
    for (int k = 0; k < CH / 256; k++) {
        int e = base + k * 256 + t;
        if (e < NEDGES) atomicAdd(&l[e2[e].y >> 9], 1);
    }
    __syncthreads();
    for (int i = t; i < NB; i += 256)
        if (l[i]) atomicAdd(&binCnt[i], l[i]);
}

__global__ __launch_bounds__(256) void k_binscan(const int* __restrict__ binCnt,
                                                 int* __restrict__ binOfs,
                                                 int* __restrict__ binCur) {
    __shared__ int sh[256];
    int t = threadIdx.x;
    int v = (t < NB) ? binCnt[t] : 0;
    sh[t] = v;
    __syncthreads();
    for (int off = 1; off < 256; off <<= 1) {
        int x = (t >= off) ? sh[t - off] : 0;
        __syncthreads();
        sh[t] += x;
        __syncthreads();
    }
    if (t < NB) {
        binOfs[t + 1] = sh[t];
        binCur[t] = sh[t] - v;      // exclusive
    }
    if (t == 0) binOfs[0] = 0;
}

// multi-split: group this block's edges by bin, one global reservation per bin.
__global__ __launch_bounds__(256) void k_binscatter(const int2* __restrict__ e2,
                                                    int* __restrict__ binCur,
                                                    int2* __restrict__ ebin) {
    __shared__ int lcnt[NB], lbase[NB], lofs[NB];
    int t = threadIdx.x;
    for (int i = t; i < NB; i += 256) lcnt[i] = 0;
    __syncthreads();
    int base = blockIdx.x * CH;
    int2 ed[CH / 256];
    int bn[CH / 256];
#pragma unroll
    for (int k = 0; k < CH / 256; k++) {
        int e = base + k * 256 + t;
        if (e < NEDGES) {
            ed[k] = e2[e];
            bn[k] = ed[k].y >> 9;
            atomicAdd(&lcnt[bn[k]], 1);
        } else bn[k] = -1;
    }
    __syncthreads();
    if (t < NB) {
        int c = lcnt[t];
        lbase[t] = c ? atomicAdd(&binCur[t], c) : 0;
        lofs[t] = 0;
    }
    __syncthreads();
#pragma unroll
    for (int k = 0; k < CH / 256; k++) {
        if (bn[k] >= 0) {
            int p = lbase[bn[k]] + atomicAdd(&lofs[bn[k]], 1);
            ebin[p] = ed[k];
        }
    }
}

// one WG per bin: local degree count -> LDS scan -> rowptr slice + perm fill.
__global__ __launch_bounds__(256) void k_binfill(const int2* __restrict__ ebin,
                                                 const int* __restrict__ binOfs,
                                                 int* __restrict__ rowptr,
                                                 int* __restrict__ perm) {
    __shared__ int deg[512], lptr[512], ssum[256];
    int b = blockIdx.x, t = threadIdx.x;
    int n0 = b << 9;
    int nn = NNODES - n0; if (nn > 512) nn = 512;
    int e0 = binOfs[b], e1 = binOfs[b + 1];
    deg[t] = 0; deg[t + 256] = 0;
    __syncthreads();
    for (int e = e0 + t; e < e1; e += 256)
        atomicAdd(&deg[ebin[e].y - n0], 1);
    __syncthreads();
    int d0 = deg[2 * t], d1 = deg[2 * t + 1];
    int s = d0 + d1;
    ssum[t] = s;
    __syncthreads();
    for (int off = 1; off < 256; off <<= 1) {
        int x = (t >= off) ? ssum[t - off] : 0;
        __syncthreads();
        ssum[t] += x;
        __syncthreads();
    }
    int ex = ssum[t] - s;
    lptr[2 * t] = ex;
    lptr[2 * t + 1] = ex + d0;
    if (2 * t < nn)     rowptr[n0 + 2 * t] = e0 + ex;
    if (2 * t + 1 < nn) rowptr[n0 + 2 * t + 1] = e0 + ex + d0;
    if (b == NB - 1 && t == 0) rowptr[NNODES] = e1;
    deg[2 * t] = 0; deg[2 * t + 1] = 0;   // reuse as cursor
    __syncthreads();
    for (int e = e0 + t; e < e1; e += 256) {
        int2 ed = ebin[e];
        int d = ed.y - n0;
        int pos = e0 + lptr[d] + atomicAdd(&deg[d], 1);
        perm[pos] = ed.x;
    }
}

// ================= gather aggregation =================
__global__ __launch_bounds__(256) void k_gather(const unsigned short* __restrict__ feat,
                                                const unsigned short* __restrict__ x,
                                                const int* __restrict__ rowptr,
                                                const int* __restrict__ perm,
                                                unsigned short* __restrict__ out) {
    int wave = threadIdx.x >> 6, lane = threadIdx.x & 63;
    int i = blockIdx.x * 4 + wave;        // NNODES = 25000*4 exactly
    const unsigned int* F = (const unsigned int*)feat;
    unsigned int xv = ((const unsigned int*)x)[i * 64 + lane];
    float accL = bf2f((unsigned short)(xv & 0xFFFFu));
    float accH = bf2f((unsigned short)(xv >> 16));
    int jb = rowptr[i], je = rowptr[i + 1];
    int j = jb;
    for (; j + 4 <= je; j += 4) {
        int s0 = perm[j], s1 = perm[j + 1], s2 = perm[j + 2], s3 = perm[j + 3];
        unsigned int v0 = F[s0 * 64 + lane];
        unsigned int v1 = F[s1 * 64 + lane];
        unsigned int v2 = F[s2 * 64 + lane];
        unsigned int v3 = F[s3 * 64 + lane];
        accL += bf2f((unsigned short)(v0 & 0xFFFFu)) + bf2f((unsigned short)(v1 & 0xFFFFu))
              + bf2f((unsigned short)(v2 & 0xFFFFu)) + bf2f((unsigned short)(v3 & 0xFFFFu));
        accH += bf2f((unsigned short)(v0 >> 16)) + bf2f((unsigned short)(v1 >> 16))
              + bf2f((unsigned short)(v2 >> 16)) + bf2f((unsigned short)(v3 >> 16));
    }
    for (; j < je; j++) {
        unsigned int v = F[perm[j] * 64 + lane];
        accL += bf2f((unsigned short)(v & 0xFFFFu));
        accH += bf2f((unsigned short)(v >> 16));
    }
    unsigned int r = ((unsigned int)f2bf(accH) << 16) | f2bf(accL);
    ((unsigned int*)out)[i * 64 + lane] = r;
}

// ---------------- fused GIN MLP: out = relu(relu(A@Wa+ba)@Wb+bb), bf16.
// Intermediate C1 round-trips through wave-private LDS (stride 136 kills the
// 16-way bank conflict of stride-128 column reads).
// Layouts (m89/m91): A[m=lane&15][k=quad*8+j]; B[k=quad*8+j][n=lane&15];
// D: col=lane&15, row=quad*4+reg.
#define C1S 136
__global__ __launch_bounds__(256) void k_gin_mlp(const unsigned short* __restrict__ A,
                                                 const unsigned short* __restrict__ WTa,
                                                 const float* __restrict__ ba,
                                                 const unsigned short* __restrict__ WTb,
                                                 const float* __restrict__ bb,
                                                 unsigned short* __restrict__ out) {
    __shared__ unsigned short c1[4][16 * C1S];
    int tid = threadIdx.x;
    int wave = tid >> 6, lane = tid & 63;
    int m = lane & 15, quad = lane >> 4;
    int tile = blockIdx.x * 4 + wave;
    if (tile > NNODES / 16 - 1) tile = NNODES / 16 - 1;   // clamp (dup stores ok)
    int r0 = tile * 16;

    const unsigned short* Ab = A + (r0 + m) * DF + quad * 8;
    bf16x8 a[4];
#pragma unroll
    for (int ks = 0; ks < 4; ks++) a[ks] = *(const bf16x8*)(Ab + ks * 32);

    f32x4 acc[8];
#pragma unroll
    for (int nt = 0; nt < 8; nt++) acc[nt] = (f32x4){0.f, 0.f, 0.f, 0.f};
#pragma unroll
    for (int nt = 0; nt < 8; nt++) {
        const unsigned short* Bb = WTa + (nt * 16 + m) * DF + quad * 8;
#pragma unroll
        for (int ks = 0; ks < 4; ks++) {
            bf16x8 b = *(const bf16x8*)(Bb + ks * 32);
            acc[nt] = __builtin_amdgcn_mfma_f32_16x16x32_bf16(a[ks], b, acc[nt], 0, 0, 0);
        }
    }
    // epilogue 1 -> LDS (D layout positions)
#pragma unroll
    for (int nt = 0; nt < 8; nt++) {
        int col = nt * 16 + m;
        float bv = ba[col];
#pragma unroll
        for (int reg = 0; reg < 4; reg++) {
            float v = acc[nt][reg] + bv;
            if (v < 0.f) v = 0.f;
            c1[wave][(quad * 4 + reg) * C1S + col] = f2bf(v);
        }
    }
    __syncthreads();

    // reload A-frags from LDS, GEMM 2
    bf16x8 a2[4];
#pragma unroll
    for (int ks = 0; ks < 4; ks++)
        a2[ks] = *(const bf16x8*)&c1[wave][m * C1S + quad * 8 + ks * 32];
#pragma unroll
    for (int nt = 0; nt < 8; nt++) acc[nt] = (f32x4){0.f, 0.f, 0.f, 0.f};
#pragma unroll
    for (int nt = 0; nt < 8; nt++) {
        const unsigned short* Bb = WTb + (nt * 16 + m) * DF + quad * 8;
#pragma unroll
        for (int ks = 0; ks < 4; ks++) {
            bf16x8 b = *(const bf16x8*)(Bb + ks * 32);
            acc[nt] = __builtin_amdgcn_mfma_f32_16x16x32_bf16(a2[ks], b, acc[nt], 0, 0, 0);
        }
    }
#pragma unroll
    for (int nt = 0; nt < 8; nt++) {
        int col = nt * 16 + m;
        float bv = bb[col];
#pragma unroll
        for (int reg = 0; reg < 4; reg++) {
            int row = r0 + quad * 4 + reg;
            float v = acc[nt][reg] + bv;
            if (v < 0.f) v = 0.f;
            out[row * DF + col] = f2bf(v);
        }
    }
}

// ---------------- fc (128 -> 40, padded 48) via MFMA + fused log_softmax.
__global__ __launch_bounds__(256) void k_fc_lsm(const unsigned short* __restrict__ A,
                                                const unsigned short* __restrict__ WfcT,
                                                const float* __restrict__ bfc,
                                                const int* __restrict__ flags,
                                                void* __restrict__ out) {
    int tid = threadIdx.x;
    int wave = tid >> 6, lane = tid & 63;
    int m = lane & 15, quad = lane >> 4;
    int tile = blockIdx.x * 4 + wave;
    int r0 = tile * 16;
    if (r0 >= NNODES) return;
    bool valid2 = (m < 8);
    int obf = flags[1];

    const unsigned short* Ab = A + (r0 + m) * DF + quad * 8;
    bf16x8 a[4];
#pragma unroll
    for (int ks = 0; ks < 4; ks++) a[ks] = *(const bf16x8*)(Ab + ks * 32);

    f32x4 acc[3];
#pragma unroll
    for (int nt = 0; nt < 3; nt++) acc[nt] = (f32x4){0.f, 0.f, 0.f, 0.f};
#pragma unroll
    for (int nt = 0; nt < 3; nt++) {
        const unsigned short* Bb = WfcT + (nt * 16 + m) * DF + quad * 8;
#pragma unroll
        for (int ks = 0; ks < 4; ks++) {
            bf16x8 b = *(const bf16x8*)(Bb + ks * 32);
            acc[nt] = __builtin_amdgcn_mfma_f32_16x16x32_bf16(a[ks], b, acc[nt], 0, 0, 0);
        }
    }

    float bv0 = bfc[m], bv1 = bfc[16 + m];
    float bv2 = valid2 ? bfc[32 + m] : 0.f;
#pragma unroll
    for (int reg = 0; reg < 4; reg++) {
        float v0 = acc[0][reg] + bv0;
        float v1 = acc[1][reg] + bv1;
        float v2 = valid2 ? (acc[2][reg] + bv2) : -3.0e38f;
        float mx = fmaxf(fmaxf(v0, v1), v2);
#pragma unroll
        for (int off = 1; off < 16; off <<= 1) mx = fmaxf(mx, __shfl_xor(mx, off, 16));
        float e = __expf(v0 - mx) + __expf(v1 - mx) + (valid2 ? __expf(v2 - mx) : 0.f);
#pragma unroll
        for (int off = 1; off < 16; off <<= 1) e += __shfl_xor(e, off, 16);
        float l = mx + __logf(e);
        int row = r0 + quad * 4 + reg;
        if (obf) {
            unsigned short* o = (unsigned short*)out + row * NC;
            o[m] = f2bf(v0 - l);
            o[16 + m] = f2bf(v1 - l);
            if (valid2) o[32 + m] = f2bf(v2 - l);
        } else {
            float* o = (float*)out + row * NC;
            o[m] = v0 - l;
            o[16 + m] = v1 - l;
            if (valid2) o[32 + m] = v2 - l;
        }
    }
}

extern "C" void kernel_launch(void* const* d_in, const int* in_sizes, int n_in,
                              void* d_out, int out_size, void* d_ws, size_t ws_size,
                              hipStream_t stream) {
    const void* x   = d_in[0];
    const void* ei  = d_in[1];
    const void* w1a = d_in[2];
    const void* b1a = d_in[3];
    const void* w1b = d_in[4];
    const void* b1b = d_in[5];
    const void* w2a = d_in[6];
    const void* b2a = d_in[7];
    const void* w2b = d_in[8];
    const void* b2b = d_in[9];
    const void* wfc = d_in[10];
    const void* bfc = d_in[11];

    char* ws = (char*)d_ws;
    size_t off = 0;
    auto alloc = [&](size_t bytes) {
        void* p = ws + off;
        off += (bytes + 255) & ~(size_t)255;
        return p;
    };
    unsigned short* B0    = (unsigned short*)alloc((size_t)NNODES * DF * 2);
    unsigned short* B1    = (unsigned short*)alloc((size_t)NNODES * DF * 2);
    unsigned short* B2    = (unsigned short*)alloc((size_t)NNODES * DF * 2);
    int2*           e2    = (int2*)alloc((size_t)NEDGES * 8);
    int2*           ebin  = (int2*)alloc((size_t)NEDGES * 8);
    int*            perm  = (int*)alloc((size_t)NEDGES * 4);
    int*            rowptr= (int*)alloc((size_t)(NNODES + 1) * 4);
    int*            binCnt= (int*)alloc(NB * 4);
    int*            binOfs= (int*)alloc((NB + 1) * 4);
    int*            binCur= (int*)alloc(NB * 4);
    int*            flags = (int*)alloc(256);
    unsigned short* wAll  = (unsigned short*)alloc((4 * 16384 + NCP * 128) * 2);
    float*          bAll  = (float*)alloc((512 + NC) * 4);

    unsigned short* w1aT = wAll;
    unsigned short* w1bT = wAll + 16384;
    unsigned short* w2aT = wAll + 32768;
    unsigned short* w2bT = wAll + 49152;
    unsigned short* wfcT = wAll + 65536;
    float* b1af = bAll;
    float* b1bf = bAll + 128;
    float* b2af = bAll + 256;
    float* b2bf = bAll + 384;
    float* bfcf = bAll + 512;

    // ---- dtype detection + canonicalization
    k_detect<<<1, 256, 0, stream>>>((const unsigned int*)ei, (const unsigned int*)x, flags);
    k_cvt_idx<<<(NEDGES + 255) / 256, 256, 0, stream>>>(ei, flags, e2);
    k_cvt_feat<<<(NNODES * DF + 255) / 256, 256, 0, stream>>>(x, flags, B0, NNODES * DF);

    int wprepN = 4 * 16384 + NCP * 128 + 512 + NC;
    k_wprep<<<(wprepN + 255) / 256, 256, 0, stream>>>(w1a, w1b, w2a, w2b, wfc,
                                                      b1a, b1b, b2a, b2b, bfc,
                                                      flags, wAll, bAll);

    // ---- binned CSR build
    hipMemsetAsync(binCnt, 0, NB * 4, stream);
    int nEB = (NEDGES + CH - 1) / CH;                          // 391
    k_bincount<<<nEB, 256, 0, stream>>>(e2, binCnt);
    k_binscan<<<1, 256, 0, stream>>>(binCnt, binOfs, binCur);
    k_binscatter<<<nEB, 256, 0, stream>>>(e2, binCur, ebin);
    k_binfill<<<NB, 256, 0, stream>>>(ebin, binOfs, rowptr, perm);

    const int gemmGrid = (NNODES / 16 + 3) / 4;                // 1563
    const int gatherGrid = NNODES / 4;                         // 25000

    // ---- layer 1
    k_gather<<<gatherGrid, 256, 0, stream>>>(B0, B0, rowptr, perm, B1);
    k_gin_mlp<<<gemmGrid, 256, 0, stream>>>(B1, w1aT, b1af, w1bT, b1bf, B2);

    // ---- layer 2
    k_gather<<<gatherGrid, 256, 0, stream>>>(B2, B2, rowptr, perm, B0);
    k_gin_mlp<<<gemmGrid, 256, 0, stream>>>(B0, w2aT, b2af, w2bT, b2bf, B1);

    // ---- fc + log_softmax
    k_fc_lsm<<<gemmGrid, 256, 0, stream>>>(B1, wfcT, bfcf, flags, d_out);
}

// Round 8
// 465.458 us; speedup vs baseline: 4.0156x; 1.0151x over previous
//
#include <hip/hip_runtime.h>
#include <hip/hip_bf16.h>

#define NNODES 100000
#define NEDGES 1600000
#define DF 128
#define NC 40
#define NCP 48          // padded fc cols (3 x 16)
#define NB 196          // CSR bins: dst>>9, 512 nodes/bin
#define CH 4096         // edges per binscatter/bincount block

typedef __bf16 bf16x8 __attribute__((ext_vector_type(8)));
typedef float f32x4 __attribute__((ext_vector_type(4)));

__device__ __forceinline__ unsigned short f2bf(float f) {
    unsigned int u = __builtin_bit_cast(unsigned int, f);
    u = (u + 0x7FFFu + ((u >> 16) & 1u)) >> 16;   // RNE
    return (unsigned short)u;
}
__device__ __forceinline__ float bf2f(unsigned short s) {
    unsigned int u = ((unsigned int)s) << 16;
    return __builtin_bit_cast(float, u);
}
__device__ __forceinline__ float bfLo(unsigned int u) {
    return __builtin_bit_cast(float, u << 16);
}
__device__ __forceinline__ float bfHi(unsigned int u) {
    return __builtin_bit_cast(float, u & 0xFFFF0000u);
}

// ---------------- dtype detection (flags[0]: ei is int64; flags[1]: floats are bf16)
__global__ void k_detect(const unsigned int* __restrict__ ei32,
                         const unsigned int* __restrict__ x32,
                         int* __restrict__ flags) {
    __shared__ unsigned int rOr[256];
    __shared__ int rCnt[256];
    unsigned int o = 0; int c = 0;
    for (int i = threadIdx.x; i < 1024; i += 256) o |= ei32[2 * i + 1];
    for (int i = threadIdx.x; i < 4096; i += 256) {
        unsigned int e = (x32[i] >> 7) & 0xFFu;
        c += (e >= 100u && e <= 140u) ? 1 : 0;
    }
    rOr[threadIdx.x] = o; rCnt[threadIdx.x] = c;
    __syncthreads();
    for (int s = 128; s; s >>= 1) {
        if ((int)threadIdx.x < s) {
            rOr[threadIdx.x] |= rOr[threadIdx.x + s];
            rCnt[threadIdx.x] += rCnt[threadIdx.x + s];
        }
        __syncthreads();
    }
    if (threadIdx.x == 0) {
        flags[0] = (rOr[0] == 0u) ? 1 : 0;
        flags[1] = (rCnt[0] > 2457) ? 1 : 0;
    }
}

__device__ __forceinline__ int ldIdx(const void* ei, int flag64, int i) {
    return flag64 ? (int)((const long long*)ei)[i] : ((const int*)ei)[i];
}

// ---------------- features -> canonical bf16
__global__ __launch_bounds__(256) void k_cvt_feat(const void* __restrict__ src,
                                                  const int* __restrict__ flags,
                                                  unsigned short* __restrict__ dst, int n) {
    int i = blockIdx.x * 256 + threadIdx.x;
    if (i >= n) return;
    dst[i] = flags[1] ? ((const unsigned short*)src)[i]
                      : f2bf(((const float*)src)[i]);
}

// ---------------- all weights (transposed bf16) + biases (fp32) in ONE launch.
__global__ __launch_bounds__(256) void k_wprep(const void* w1a, const void* w1b,
                                               const void* w2a, const void* w2b,
                                               const void* wfc,
                                               const void* b1a, const void* b1b,
                                               const void* b2a, const void* b2b,
                                               const void* bfc,
                                               const int* __restrict__ flags,
                                               unsigned short* __restrict__ wAll,
                                               float* __restrict__ bAll) {
    int idx = blockIdx.x * 256 + threadIdx.x;
    int bf = flags[1];
    auto ldf = [&](const void* p, int i) -> float {
        return bf ? bf2f(((const unsigned short*)p)[i]) : ((const float*)p)[i];
    };
    if (idx < 65536) {                       // 4 square transposes
        int wi = idx >> 14, r = idx & 16383;
        int n = r >> 7, k = r & 127;
        const void* s = (wi == 0) ? w1a : (wi == 1) ? w1b : (wi == 2) ? w2a : w2b;
        wAll[idx] = f2bf(ldf(s, k * 128 + n));
    } else if (idx < 65536 + NCP * 128) {    // wfc transpose, zero pad
        int r = idx - 65536;
        int n = r >> 7, k = r & 127;
        wAll[idx] = (n < NC) ? f2bf(ldf(wfc, k * NC + n)) : (unsigned short)0;
    } else if (idx < 65536 + NCP * 128 + 512 + NC) {
        int r = idx - (65536 + NCP * 128);
        const void* s; int i;
        if (r < 128)      { s = b1a; i = r; }
        else if (r < 256) { s = b1b; i = r - 128; }
        else if (r < 384) { s = b2a; i = r - 256; }
        else if (r < 512) { s = b2b; i = r - 384; }
        else              { s = bfc; i = r - 512; }
        bAll[r] = ldf(s, i);
    }
}

// ================= binned CSR build =================
// bin = dst >> 9 (196 bins). bincount -> binscan -> binscatter -> binfill.
__global__ __launch_bounds__(256) void k_bincount(const void* __restrict__ ei,
                                                  const int* __restrict__ flags,
                                                  int* __restrict__ binCnt) {
    __shared__ int l[NB];
    int t = threadIdx.x;
    int f64 = flags[0];
    for (int i = t; i < NB; i += 256) l[i] = 0;
    __syncthreads();
    int base = blockIdx.x * CH;
#pragma unroll
    for (int k = 0; k < CH / 256; k++) {
        int e = base + k * 256 + t;
        if (e < NEDGES) atomicAdd(&l[ldIdx(ei, f64, NEDGES + e) >> 9], 1);
    }
    __syncthreads();
    for (int i = t; i < NB; i += 256)
        if (l[i]) atomicAdd(&binCnt[i], l[i]);
}

__global__ __launch_bounds__(256) void k_binscan(const int* __restrict__ binCnt,
                                                 int* __restrict__ binOfs,
                                                 int* __restrict__ binCur) {
    __shared__ int sh[256];
    int t = threadIdx.x;
    int v = (t < NB) ? binCnt[t] : 0;
    sh[t] = v;
    __syncthreads();
    for (int off = 1; off < 256; off <<= 1) {
        int x = (t >= off) ? sh[t - off] : 0;
        __syncthreads();
        sh[t] += x;
        __syncthreads();
    }
    if (t < NB) {
        binOfs[t + 1] = sh[t];
        binCur[t] = sh[t] - v;      // exclusive
    }
    if (t == 0) binOfs[0] = 0;
}

// multi-split: group this block's edges by bin, one global reservation per bin.
__global__ __launch_bounds__(256) void k_binscatter(const void* __restrict__ ei,
                                                    const int* __restrict__ flags,
                                                    int* __restrict__ binCur,
                                                    int2* __restrict__ ebin) {
    __shared__ int lcnt[NB], lbase[NB], lofs[NB];
    int t = threadIdx.x;
    int f64 = flags[0];
    for (int i = t; i < NB; i += 256) lcnt[i] = 0;
    __syncthreads();
    int base = blockIdx.x * CH;
    int2 ed[CH / 256];
    int bn[CH / 256];
#pragma unroll
    for (int k = 0; k < CH / 256; k++) {
        int e = base + k * 256 + t;
        if (e < NEDGES) {
            ed[k].x = ldIdx(ei, f64, e);
            ed[k].y = ldIdx(ei, f64, NEDGES + e);
            bn[k] = ed[k].y >> 9;
            atomicAdd(&lcnt[bn[k]], 1);
        } else bn[k] = -1;
    }
    __syncthreads();
    if (t < NB) {
        int c = lcnt[t];
        lbase[t] = c ? atomicAdd(&binCur[t], c) : 0;
        lofs[t] = 0;
    }
    __syncthreads();
#pragma unroll
    for (int k = 0; k < CH / 256; k++) {
        if (bn[k] >= 0) {
            int p = lbase[bn[k]] + atomicAdd(&lofs[bn[k]], 1);
            ebin[p] = ed[k];
        }
    }
}

// one WG per bin: local degree count -> LDS scan -> rowptr slice + perm fill.
__global__ __launch_bounds__(256) void k_binfill(const int2* __restrict__ ebin,
                                                 const int* __restrict__ binOfs,
                                                 int* __restrict__ rowptr,
                                                 int* __restrict__ perm) {
    __shared__ int deg[512], lptr[512], ssum[256];
    int b = blockIdx.x, t = threadIdx.x;
    int n0 = b << 9;
    int nn = NNODES - n0; if (nn > 512) nn = 512;
    int e0 = binOfs[b], e1 = binOfs[b + 1];
    deg[t] = 0; deg[t + 256] = 0;
    __syncthreads();
    for (int e = e0 + t; e < e1; e += 256)
        atomicAdd(&deg[ebin[e].y - n0], 1);
    __syncthreads();
    int d0 = deg[2 * t], d1 = deg[2 * t + 1];
    int s = d0 + d1;
    ssum[t] = s;
    __syncthreads();
    for (int off = 1; off < 256; off <<= 1) {
        int x = (t >= off) ? ssum[t - off] : 0;
        __syncthreads();
        ssum[t] += x;
        __syncthreads();
    }
    int ex = ssum[t] - s;
    lptr[2 * t] = ex;
    lptr[2 * t + 1] = ex + d0;
    if (2 * t < nn)     rowptr[n0 + 2 * t] = e0 + ex;
    if (2 * t + 1 < nn) rowptr[n0 + 2 * t + 1] = e0 + ex + d0;
    if (b == NB - 1 && t == 0) rowptr[NNODES] = e1;
    deg[2 * t] = 0; deg[2 * t + 1] = 0;   // reuse as cursor
    __syncthreads();
    for (int e = e0 + t; e < e1; e += 256) {
        int2 ed = ebin[e];
        int d = ed.y - n0;
        int pos = e0 + lptr[d] + atomicAdd(&deg[d], 1);
        perm[pos] = ed.x;
    }
}

// ================= gather aggregation =================
// out[i] = bf16( x[i] + sum_neighbors feat[perm[j]] ); 8-edge unroll for MLP.
__global__ __launch_bounds__(256) void k_gather(const unsigned short* __restrict__ feat,
                                                const unsigned short* __restrict__ x,
                                                const int* __restrict__ rowptr,
                                                const int* __restrict__ perm,
                                                unsigned short* __restrict__ out) {
    int wave = threadIdx.x >> 6, lane = threadIdx.x & 63;
    int i = blockIdx.x * 4 + wave;        // NNODES = 25000*4 exactly
    const unsigned int* F = (const unsigned int*)feat;
    unsigned int xv = ((const unsigned int*)x)[i * 64 + lane];
    float accL = bfLo(xv);
    float accH = bfHi(xv);
    int jb = rowptr[i], je = rowptr[i + 1];
    int j = jb;
    for (; j + 8 <= je; j += 8) {
        int s[8];
#pragma unroll
        for (int k = 0; k < 8; k++) s[k] = perm[j + k];
        unsigned int v[8];
#pragma unroll
        for (int k = 0; k < 8; k++) v[k] = F[s[k] * 64 + lane];
#pragma unroll
        for (int k = 0; k < 8; k++) {
            accL += bfLo(v[k]);
            accH += bfHi(v[k]);
        }
    }
    for (; j < je; j++) {
        unsigned int v = F[perm[j] * 64 + lane];
        accL += bfLo(v);
        accH += bfHi(v);
    }
    unsigned int r = ((unsigned int)f2bf(accH) << 16) | f2bf(accL);
    ((unsigned int*)out)[i * 64 + lane] = r;
}

// ---------------- fused GIN MLP: out = relu(relu(A@Wa+ba)@Wb+bb), bf16.
// Intermediate round-trips through wave-private LDS (stride 136 breaks the
// 16-way bank conflict of stride-128 column reads).
// Layouts (m89/m91): A[m=lane&15][k=quad*8+j]; B[k=quad*8+j][n=lane&15];
// D: col=lane&15, row=quad*4+reg.
#define C1S 136
__global__ __launch_bounds__(256) void k_gin_mlp(const unsigned short* __restrict__ A,
                                                 const unsigned short* __restrict__ WTa,
                                                 const float* __restrict__ ba,
                                                 const unsigned short* __restrict__ WTb,
                                                 const float* __restrict__ bb,
                                                 unsigned short* __restrict__ out) {
    __shared__ unsigned short c1[4][16 * C1S];
    int tid = threadIdx.x;
    int wave = tid >> 6, lane = tid & 63;
    int m = lane & 15, quad = lane >> 4;
    int tile = blockIdx.x * 4 + wave;
    if (tile > NNODES / 16 - 1) tile = NNODES / 16 - 1;   // clamp (dup stores ok)
    int r0 = tile * 16;

    const unsigned short* Ab = A + (r0 + m) * DF + quad * 8;
    bf16x8 a[4];
#pragma unroll
    for (int ks = 0; ks < 4; ks++) a[ks] = *(const bf16x8*)(Ab + ks * 32);

    f32x4 acc[8];
#pragma unroll
    for (int nt = 0; nt < 8; nt++) acc[nt] = (f32x4){0.f, 0.f, 0.f, 0.f};
#pragma unroll
    for (int nt = 0; nt < 8; nt++) {
        const unsigned short* Bb = WTa + (nt * 16 + m) * DF + quad * 8;
#pragma unroll
        for (int ks = 0; ks < 4; ks++) {
            bf16x8 b = *(const bf16x8*)(Bb + ks * 32);
            acc[nt] = __builtin_amdgcn_mfma_f32_16x16x32_bf16(a[ks], b, acc[nt], 0, 0, 0);
        }
    }
#pragma unroll
    for (int nt = 0; nt < 8; nt++) {
        int col = nt * 16 + m;
        float bv = ba[col];
#pragma unroll
        for (int reg = 0; reg < 4; reg++) {
            float v = acc[nt][reg] + bv;
            if (v < 0.f) v = 0.f;
            c1[wave][(quad * 4 + reg) * C1S + col] = f2bf(v);
        }
    }
    __syncthreads();

    bf16x8 a2[4];
#pragma unroll
    for (int ks = 0; ks < 4; ks++)
        a2[ks] = *(const bf16x8*)&c1[wave][m * C1S + quad * 8 + ks * 32];
#pragma unroll
    for (int nt = 0; nt < 8; nt++) acc[nt] = (f32x4){0.f, 0.f, 0.f, 0.f};
#pragma unroll
    for (int nt = 0; nt < 8; nt++) {
        const unsigned short* Bb = WTb + (nt * 16 + m) * DF + quad * 8;
#pragma unroll
        for (int ks = 0; ks < 4; ks++) {
            bf16x8 b = *(const bf16x8*)(Bb + ks * 32);
            acc[nt] = __builtin_amdgcn_mfma_f32_16x16x32_bf16(a2[ks], b, acc[nt], 0, 0, 0);
        }
    }
#pragma unroll
    for (int nt = 0; nt < 8; nt++) {
        int col = nt * 16 + m;
        float bv = bb[col];
#pragma unroll
        for (int reg = 0; reg < 4; reg++) {
            int row = r0 + quad * 4 + reg;
            float v = acc[nt][reg] + bv;
            if (v < 0.f) v = 0.f;
            out[row * DF + col] = f2bf(v);
        }
    }
}

// ---------------- layer-2 MLP + fc(40, padded 48) + log_softmax, fully fused.
// H2 never leaves the CU: GEMM-a -> LDS -> GEMM-b -> LDS -> fc GEMM -> lsm.
__global__ __launch_bounds__(256) void k_gin_mlp_fc(const unsigned short* __restrict__ A,
                                                    const unsigned short* __restrict__ WTa,
                                                    const float* __restrict__ ba,
                                                    const unsigned short* __restrict__ WTb,
                                                    const float* __restrict__ bb,
                                                    const unsigned short* __restrict__ WfcT,
                                                    const float* __restrict__ bfc,
                                                    const int* __restrict__ flags,
                                                    void* __restrict__ out) {
    __shared__ unsigned short c1[4][16 * C1S];
    int tid = threadIdx.x;
    int wave = tid >> 6, lane = tid & 63;
    int m = lane & 15, quad = lane >> 4;
    int tile = blockIdx.x * 4 + wave;
    if (tile > NNODES / 16 - 1) tile = NNODES / 16 - 1;   // clamp (dup stores ok)
    int r0 = tile * 16;

    const unsigned short* Ab = A + (r0 + m) * DF + quad * 8;
    bf16x8 a[4];
#pragma unroll
    for (int ks = 0; ks < 4; ks++) a[ks] = *(const bf16x8*)(Ab + ks * 32);

    f32x4 acc[8];
#pragma unroll
    for (int nt = 0; nt < 8; nt++) acc[nt] = (f32x4){0.f, 0.f, 0.f, 0.f};
#pragma unroll
    for (int nt = 0; nt < 8; nt++) {
        const unsigned short* Bb = WTa + (nt * 16 + m) * DF + quad * 8;
#pragma unroll
        for (int ks = 0; ks < 4; ks++) {
            bf16x8 b = *(const bf16x8*)(Bb + ks * 32);
            acc[nt] = __builtin_amdgcn_mfma_f32_16x16x32_bf16(a[ks], b, acc[nt], 0, 0, 0);
        }
    }
#pragma unroll
    for (int nt = 0; nt < 8; nt++) {
        int col = nt * 16 + m;
        float bv = ba[col];
#pragma unroll
        for (int reg = 0; reg < 4; reg++) {
            float v = acc[nt][reg] + bv;
            if (v < 0.f) v = 0.f;
            c1[wave][(quad * 4 + reg) * C1S + col] = f2bf(v);
        }
    }
    __syncthreads();

    bf16x8 a2[4];
#pragma unroll
    for (int ks = 0; ks < 4; ks++)
        a2[ks] = *(const bf16x8*)&c1[wave][m * C1S + quad * 8 + ks * 32];
#pragma unroll
    for (int nt = 0; nt < 8; nt++) acc[nt] = (f32x4){0.f, 0.f, 0.f, 0.f};
#pragma unroll
    for (int nt = 0; nt < 8; nt++) {
        const unsigned short* Bb = WTb + (nt * 16 + m) * DF + quad * 8;
#pragma unroll
        for (int ks = 0; ks < 4; ks++) {
            bf16x8 b = *(const bf16x8*)(Bb + ks * 32);
            acc[nt] = __builtin_amdgcn_mfma_f32_16x16x32_bf16(a2[ks], b, acc[nt], 0, 0, 0);
        }
    }
    __syncthreads();   // c1 reuse for H2
#pragma unroll
    for (int nt = 0; nt < 8; nt++) {
        int col = nt * 16 + m;
        float bv = bb[col];
#pragma unroll
        for (int reg = 0; reg < 4; reg++) {
            float v = acc[nt][reg] + bv;
            if (v < 0.f) v = 0.f;
            c1[wave][(quad * 4 + reg) * C1S + col] = f2bf(v);
        }
    }
    __syncthreads();

    // fc GEMM from LDS H2
    bf16x8 a3[4];
#pragma unroll
    for (int ks = 0; ks < 4; ks++)
        a3[ks] = *(const bf16x8*)&c1[wave][m * C1S + quad * 8 + ks * 32];
    f32x4 fco[3];
#pragma unroll
    for (int nt = 0; nt < 3; nt++) fco[nt] = (f32x4){0.f, 0.f, 0.f, 0.f};
#pragma unroll
    for (int nt = 0; nt < 3; nt++) {
        const unsigned short* Bb = WfcT + (nt * 16 + m) * DF + quad * 8;
#pragma unroll
        for (int ks = 0; ks < 4; ks++) {
            bf16x8 b = *(const bf16x8*)(Bb + ks * 32);
            fco[nt] = __builtin_amdgcn_mfma_f32_16x16x32_bf16(a3[ks], b, fco[nt], 0, 0, 0);
        }
    }

    bool valid2 = (m < 8);
    int obf = flags[1];
    float bv0 = bfc[m], bv1 = bfc[16 + m];
    float bv2 = valid2 ? bfc[32 + m] : 0.f;
#pragma unroll
    for (int reg = 0; reg < 4; reg++) {
        float v0 = fco[0][reg] + bv0;
        float v1 = fco[1][reg] + bv1;
        float v2 = valid2 ? (fco[2][reg] + bv2) : -3.0e38f;
        float mx = fmaxf(fmaxf(v0, v1), v2);
#pragma unroll
        for (int off = 1; off < 16; off <<= 1) mx = fmaxf(mx, __shfl_xor(mx, off, 16));
        float e = __expf(v0 - mx) + __expf(v1 - mx) + (valid2 ? __expf(v2 - mx) : 0.f);
#pragma unroll
        for (int off = 1; off < 16; off <<= 1) e += __shfl_xor(e, off, 16);
        float l = mx + __logf(e);
        int row = r0 + quad * 4 + reg;
        if (obf) {
            unsigned short* o = (unsigned short*)out + row * NC;
            o[m] = f2bf(v0 - l);
            o[16 + m] = f2bf(v1 - l);
            if (valid2) o[32 + m] = f2bf(v2 - l);
        } else {
            float* o = (float*)out + row * NC;
            o[m] = v0 - l;
            o[16 + m] = v1 - l;
            if (valid2) o[32 + m] = v2 - l;
        }
    }
}

extern "C" void kernel_launch(void* const* d_in, const int* in_sizes, int n_in,
                              void* d_out, int out_size, void* d_ws, size_t ws_size,
                              hipStream_t stream) {
    const void* x   = d_in[0];
    const void* ei  = d_in[1];
    const void* w1a = d_in[2];
    const void* b1a = d_in[3];
    const void* w1b = d_in[4];
    const void* b1b = d_in[5];
    const void* w2a = d_in[6];
    const void* b2a = d_in[7];
    const void* w2b = d_in[8];
    const void* b2b = d_in[9];
    const void* wfc = d_in[10];
    const void* bfc = d_in[11];

    char* ws = (char*)d_ws;
    size_t off = 0;
    auto alloc = [&](size_t bytes) {
        void* p = ws + off;
        off += (bytes + 255) & ~(size_t)255;
        return p;
    };
    unsigned short* B0    = (unsigned short*)alloc((size_t)NNODES * DF * 2);
    unsigned short* B1    = (unsigned short*)alloc((size_t)NNODES * DF * 2);
    unsigned short* B2    = (unsigned short*)alloc((size_t)NNODES * DF * 2);
    int2*           ebin  = (int2*)alloc((size_t)NEDGES * 8);
    int*            perm  = (int*)alloc((size_t)NEDGES * 4);
    int*            rowptr= (int*)alloc((size_t)(NNODES + 1) * 4);
    int*            binCnt= (int*)alloc(NB * 4);
    int*            binOfs= (int*)alloc((NB + 1) * 4);
    int*            binCur= (int*)alloc(NB * 4);
    int*            flags = (int*)alloc(256);
    unsigned short* wAll  = (unsigned short*)alloc((4 * 16384 + NCP * 128) * 2);
    float*          bAll  = (float*)alloc((512 + NC) * 4);

    unsigned short* w1aT = wAll;
    unsigned short* w1bT = wAll + 16384;
    unsigned short* w2aT = wAll + 32768;
    unsigned short* w2bT = wAll + 49152;
    unsigned short* wfcT = wAll + 65536;
    float* b1af = bAll;
    float* b1bf = bAll + 128;
    float* b2af = bAll + 256;
    float* b2bf = bAll + 384;
    float* bfcf = bAll + 512;

    // ---- dtype detection + canonicalization
    k_detect<<<1, 256, 0, stream>>>((const unsigned int*)ei, (const unsigned int*)x, flags);
    k_cvt_feat<<<(NNODES * DF + 255) / 256, 256, 0, stream>>>(x, flags, B0, NNODES * DF);

    int wprepN = 4 * 16384 + NCP * 128 + 512 + NC;
    k_wprep<<<(wprepN + 255) / 256, 256, 0, stream>>>(w1a, w1b, w2a, w2b, wfc,
                                                      b1a, b1b, b2a, b2b, bfc,
                                                      flags, wAll, bAll);

    // ---- binned CSR build (reads edge_index directly)
    hipMemsetAsync(binCnt, 0, NB * 4, stream);
    int nEB = (NEDGES + CH - 1) / CH;                          // 391
    k_bincount<<<nEB, 256, 0, stream>>>(ei, flags, binCnt);
    k_binscan<<<1, 256, 0, stream>>>(binCnt, binOfs, binCur);
    k_binscatter<<<nEB, 256, 0, stream>>>(ei, flags, binCur, ebin);
    k_binfill<<<NB, 256, 0, stream>>>(ebin, binOfs, rowptr, perm);

    const int gemmGrid = (NNODES / 16 + 3) / 4;                // 1563
    const int gatherGrid = NNODES / 4;                         // 25000

    // ---- layer 1
    k_gather<<<gatherGrid, 256, 0, stream>>>(B0, B0, rowptr, perm, B1);
    k_gin_mlp<<<gemmGrid, 256, 0, stream>>>(B1, w1aT, b1af, w1bT, b1bf, B2);

    // ---- layer 2 + fc + log_softmax (fused)
    k_gather<<<gatherGrid, 256, 0, stream>>>(B2, B2, rowptr, perm, B0);
    k_gin_mlp_fc<<<gemmGrid, 256, 0, stream>>>(B0, w2aT, b2af, w2bT, b2bf,
                                               wfcT, bfcf, flags, d_out);
}